// Round 9
// baseline (542.533 us; speedup 1.0000x reference)
//
#include <hip/hip_runtime.h>
#include <hip/hip_bf16.h>
#include <stdint.h>

#define BB   8
#define LL   1024
#define LOO  1024
#define HH   768
#define VV   4096
#define OUTW 5120   // VV + LL
#define EMAX 256    // tags sorted from [0,256) => emitted <= 255

typedef unsigned short ushort_t;
typedef __attribute__((ext_vector_type(4))) float   f32x4;
typedef __attribute__((ext_vector_type(8))) __bf16  bf16x8;
typedef __attribute__((ext_vector_type(4))) float   float4v;
typedef __attribute__((ext_vector_type(4))) int     int4v;

static __device__ __forceinline__ ushort_t f2bf(float f) {
    union { float f; uint32_t u; } v; v.f = f;
    uint32_t u = v.u;
    uint32_t r = (u + 0x7fffu + ((u >> 16) & 1u)) >> 16;
    return (ushort_t)r;
}

// Single fused kernel, 1088 blocks x 512 threads.
// Blocks [0,64): GEMM over out cols [VV,VV+256), tile 128x256, BK=64.
//   B-tile (attn segment means) computed IN-BLOCK from h1 + tags each K-chunk
//   (no attn workspace, no prologue kernel). A staged f32->bf16. XOR-swizzled
//   LDS both operands (write and read sides use the same involution).
// Blocks [64,1088): copy lm -> out[:,0:VV] and fill [VV+256,VV+LL) = -100,
//   plain float4 (m13/fill evidence: plain > nt).
#define NGEMM 64

struct SMem {
    union {
        struct { int stags[LL]; int cnt[512]; } scan;   // 6 KB, scan phase only
        char Bs[256 * 128];                             // 32 KB B tile [256][128B]
    } u;
    char As[128 * 128];                                 // 16 KB A tile [128][128B]
    int  runpos[EMAX + 4];
};

__global__ __launch_bounds__(512, 4) void fused_single_kernel(
        const float* __restrict__ h1,      // [BB][LL][HH]
        const float* __restrict__ h2,      // [BB][LOO][HH]
        const float* __restrict__ lm,      // [BB][LOO][VV]
        const int*   __restrict__ tags,    // [BB][LL]
        float*       __restrict__ out) {   // [BB][LOO][OUTW]
    __shared__ SMem sm;

    const int bid = blockIdx.x;
    const int tid = threadIdx.x;

    if (bid >= NGEMM) {
        // ---------------- copy + fill path (plain stores) ----------------
        int cid = bid - NGEMM;             // 0..1023, 8 out-rows each
        const float4v* lm4 = (const float4v*)lm + (size_t)cid * 8 * 1024;
        float4v* o4 = (float4v*)out + (size_t)cid * 8 * 1280;
        const float4v fv = {-100.f, -100.f, -100.f, -100.f};
#pragma unroll 2
        for (int r = 0; r < 8; r += 2) {
            float4v v0 = lm4[(size_t)(r    ) * 1024 + tid];
            float4v v1 = lm4[(size_t)(r    ) * 1024 + tid + 512];
            float4v v2 = lm4[(size_t)(r + 1) * 1024 + tid];
            float4v v3 = lm4[(size_t)(r + 1) * 1024 + tid + 512];
            o4[(size_t)(r    ) * 1280 + tid]       = v0;
            o4[(size_t)(r    ) * 1280 + tid + 512] = v1;
            o4[(size_t)(r + 1) * 1280 + tid]       = v2;
            o4[(size_t)(r + 1) * 1280 + tid + 512] = v3;
            if (tid < 192) {
                o4[(size_t)(r    ) * 1280 + 1088 + tid] = fv;
                o4[(size_t)(r + 1) * 1280 + 1088 + tid] = fv;
            }
        }
        return;
    }

    // ================= GEMM path =================
    const int b  = bid >> 3;               // batch
    const int rt = bid & 7;                // row tile
    const int R0 = rt << 7;                // first of 128 h2 rows
    const int lane = tid & 63;
    const int wv   = tid >> 6;             // wave 0..7
    const int wr   = wv >> 1;              // 0..3 : M sub (32 rows)
    const int wc   = wv & 1;               // 0..1 : N half (128 cols)

    // ---- tag scan (512 threads, 2 tags each) ----
    if (tid < 256)
        ((int4v*)sm.u.scan.stags)[tid] = ((const int4v*)(tags + b * LL))[tid];
    __syncthreads();
    int p0 = tid * 2;
    int prev = (p0 == 0) ? -2 : sm.u.scan.stags[p0 - 1];
    int s0 = (sm.u.scan.stags[p0] != prev);
    int s1 = (sm.u.scan.stags[p0 + 1] != sm.u.scan.stags[p0]);
    int c2 = s0 + s1;
    sm.u.scan.cnt[tid] = c2;
    __syncthreads();
    for (int off = 1; off < 512; off <<= 1) {
        int v = sm.u.scan.cnt[tid];
        int a = (tid >= off) ? sm.u.scan.cnt[tid - off] : 0;
        __syncthreads();
        sm.u.scan.cnt[tid] = v + a;
        __syncthreads();
    }
    const int total = sm.u.scan.cnt[511];      // runs (<= 256, tags sorted)
    const int em    = total - 1;               // trailing open run dropped
    {
        int base = sm.u.scan.cnt[tid] - c2;
        if (s0) sm.runpos[base++] = p0;
        if (s1) sm.runpos[base]   = p0 + 1;
        if (tid == 0) { sm.runpos[total] = LL; sm.runpos[total + 1] = 0x7fffffff; }
    }
    __syncthreads();                           // runpos final; scan scratch dead

    // ---- per-wave segment range (uniform within wave) ----
    int slo, shi;
    {
        int t0 = wv << 7, t1 = t0 + 128;
        int a = 0, z = total;
        while (a < z) { int m = (a + z) >> 1; if (sm.runpos[m] < t0) a = m + 1; else z = m; }
        slo = a;
        z = total;
        while (a < z) { int m = (a + z) >> 1; if (sm.runpos[m] < t1) a = m + 1; else z = m; }
        shi = a;
    }
    const int pstart = sm.runpos[slo];
    const int pend   = sm.runpos[shi];

    const float* Ab = h2 + ((size_t)b * LOO + R0) * HH;
    const float* hb = h1 + (size_t)b * LL * HH + lane;   // lane = col within chunk

    f32x4 acc0[8], acc1[8];
#pragma unroll
    for (int i = 0; i < 8; ++i) {
        acc0[i] = (f32x4){0.f, 0.f, 0.f, 0.f};
        acc1[i] = (f32x4){0.f, 0.f, 0.f, 0.f};
    }

    const int arow = tid >> 2;                 // A-stage row 0..127
    const int aq   = tid & 3;                  // 16-f32 quad group
    const int axr  = (arow & 7) << 4;

    for (int kc = 0; kc < 12; ++kc) {
        const int k0 = kc << 6;
        // ---- stage A: 128x64 f32 -> bf16, XOR-swizzled ----
        {
            const float* pa = Ab + (size_t)arow * HH + k0 + aq * 16;
            f32x4 v0 = ((const f32x4*)pa)[0];
            f32x4 v1 = ((const f32x4*)pa)[1];
            f32x4 v2 = ((const f32x4*)pa)[2];
            f32x4 v3 = ((const f32x4*)pa)[3];
            bf16x8 t0, t1;
            t0[0] = (__bf16)v0[0]; t0[1] = (__bf16)v0[1]; t0[2] = (__bf16)v0[2]; t0[3] = (__bf16)v0[3];
            t0[4] = (__bf16)v1[0]; t0[5] = (__bf16)v1[1]; t0[6] = (__bf16)v1[2]; t0[7] = (__bf16)v1[3];
            t1[0] = (__bf16)v2[0]; t1[1] = (__bf16)v2[1]; t1[2] = (__bf16)v2[2]; t1[3] = (__bf16)v2[3];
            t1[4] = (__bf16)v3[0]; t1[5] = (__bf16)v3[1]; t1[6] = (__bf16)v3[2]; t1[7] = (__bf16)v3[3];
            *(bf16x8*)(sm.As + arow * 128 + ((aq * 32     ) ^ axr)) = t0;
            *(bf16x8*)(sm.As + arow * 128 + ((aq * 32 + 16) ^ axr)) = t1;
        }
        // ---- compute B tile rows [slo,shi): stream rows, flush at boundaries ----
        {
            float sum = 0.f;
            int s = slo, segst = pstart, nb = sm.runpos[slo + 1];
            const float* hp = hb + k0;
#pragma unroll 4
            for (int p = pstart; p < pend; ++p) {
                sum += hp[(size_t)p * HH];
                if (p + 1 == nb) {               // uniform across wave
                    float m = sum / (float)(nb - segst);
                    *(ushort_t*)(sm.u.Bs + s * 128 + ((lane * 2) ^ ((s & 7) << 4))) = f2bf(m);
                    sum = 0.f; segst = nb; ++s; nb = sm.runpos[s + 1];
                }
            }
        }
        __syncthreads();

        // ---- fragments + MFMA (rows >= em hold garbage; epilogue discards) ----
        const int g16 = (lane >> 4) << 4;
        const int r0a = (wr << 5) + (lane & 15);
        const int r1a = r0a + 16;
#pragma unroll
        for (int ksub = 0; ksub < 2; ++ksub) {
            const int kb = (ksub << 6) + g16;
            bf16x8 af0 = *(const bf16x8*)(sm.As + r0a * 128 + (kb ^ ((r0a & 7) << 4)));
            bf16x8 af1 = *(const bf16x8*)(sm.As + r1a * 128 + (kb ^ ((r1a & 7) << 4)));
#pragma unroll
            for (int ni = 0; ni < 8; ++ni) {
                int rb = (wc << 7) + (ni << 4) + (lane & 15);
                bf16x8 bf = *(const bf16x8*)(sm.u.Bs + rb * 128 + (kb ^ ((rb & 7) << 4)));
                acc0[ni] = __builtin_amdgcn_mfma_f32_16x16x32_bf16(af0, bf, acc0[ni], 0, 0, 0);
                acc1[ni] = __builtin_amdgcn_mfma_f32_16x16x32_bf16(af1, bf, acc1[ni], 0, 0, 0);
            }
        }
        __syncthreads();
    }

    // ---- epilogue: C/D layout col=lane&15, row=(lane>>4)*4+reg ----
    float* outb = out + ((size_t)b * LOO + R0) * OUTW + VV;
    const int rb0 = (wr << 5) + ((lane >> 4) << 2);
#pragma unroll
    for (int ni = 0; ni < 8; ++ni) {
        int l = (wc << 7) + (ni << 4) + (lane & 15);
        bool live = (l < em);
#pragma unroll
        for (int rr = 0; rr < 4; ++rr) {
            outb[(size_t)(rb0 + rr) * OUTW + l]      = live ? acc0[ni][rr] : -100.f;
            outb[(size_t)(rb0 + 16 + rr) * OUTW + l] = live ? acc1[ni][rr] : -100.f;
        }
    }
}

extern "C" void kernel_launch(void* const* d_in, const int* in_sizes, int n_in,
                              void* d_out, int out_size, void* d_ws, size_t ws_size,
                              hipStream_t stream) {
    const float* h1   = (const float*)d_in[0];   // [8,1024,768]
    const float* h2   = (const float*)d_in[1];   // [8,1024,768]
    const float* lm   = (const float*)d_in[2];   // [8,1024,4096]
    const int*   tags = (const int*)d_in[3];     // [8,1024]
    float* out = (float*)d_out;                  // [8,1024,5120]

    fused_single_kernel<<<NGEMM + 1024, 512, 0, stream>>>(h1, h2, lm, tags, out);
}

// Round 10
// 192.899 us; speedup vs baseline: 2.8125x; 2.8125x over previous
//
#include <hip/hip_runtime.h>
#include <hip/hip_bf16.h>
#include <stdint.h>

#define BB   8
#define LL   1024
#define LOO  1024
#define HH   768
#define VV   4096
#define OUTW 5120   // VV + LL
#define EMAX 256    // tags sorted from [0,256) => emitted <= 255

typedef unsigned short ushort_t;
typedef __attribute__((ext_vector_type(4))) float   f32x4;
typedef __attribute__((ext_vector_type(8))) __bf16  bf16x8;
typedef __attribute__((ext_vector_type(4))) float   float4v;
typedef __attribute__((ext_vector_type(4))) int     int4v;

static __device__ __forceinline__ ushort_t f2bf(float f) {
    union { float f; uint32_t u; } v; v.f = f;
    uint32_t u = v.u;
    uint32_t r = (u + 0x7fffu + ((u >> 16) & 1u)) >> 16;
    return (ushort_t)r;
}

// Single mega kernel, 4224 blocks x 256 threads, three classes in grid order:
//  [0,2048):    attn producers (R2 logic): block (b,r) -> attn row r of batch b,
//               then release-increment done[b].
//  [2048,2176): GEMM blocks: spin (acquire) until done[b]==256, then R2's
//               proven 128x128 LDS GEMM over out cols [VV,VV+256).
//  [2176,4224): copy blocks: R2's plain-float4 lm->out copy + (-100) fill.
#define NATTN 2048
#define NGEMMB 128
#define NCOPY 2048

struct SM {
    union {
        struct { int stags[LL]; int cnt[256]; int runpos[EMAX + 2]; } a;
        char g[49152];   // GEMM: A f32 32KB @0, B bf16 16KB @32768
    } u;
};

__global__ __launch_bounds__(256, 2) void mega_kernel(
        const float* __restrict__ h1,      // [BB][LL][HH]
        const float* __restrict__ h2,      // [BB][LOO][HH]
        const float* __restrict__ lm,      // [BB][LOO][VV]
        const int*   __restrict__ tags,    // [BB][LL]
        ushort_t*    __restrict__ attn,    // ws bf16 [BB][EMAX][HH]
        int*         __restrict__ done,    // ws [BB], zeroed via memsetAsync
        float*       __restrict__ out) {   // [BB][LOO][OUTW]
    __shared__ SM sm;
    const int bid = blockIdx.x;
    const int tid = threadIdx.x;

    if (bid < NATTN) {
        // ================= attn producer =================
        int b = bid >> 8;
        int r = bid & 255;

        ((int4v*)sm.u.a.stags)[tid] = ((const int4v*)(tags + b * LL))[tid];
        __syncthreads();

        int p0 = tid * 4;
        int st[4];
        int prevm1 = (p0 == 0) ? -2 : sm.u.a.stags[p0 - 1];
        st[0] = (p0 == 0) || (sm.u.a.stags[p0] != prevm1);
        st[1] = (sm.u.a.stags[p0 + 1] != sm.u.a.stags[p0]);
        st[2] = (sm.u.a.stags[p0 + 2] != sm.u.a.stags[p0 + 1]);
        st[3] = (sm.u.a.stags[p0 + 3] != sm.u.a.stags[p0 + 2]);
        int c = st[0] + st[1] + st[2] + st[3];
        sm.u.a.cnt[tid] = c;
        __syncthreads();
        for (int off = 1; off < 256; off <<= 1) {
            int v = sm.u.a.cnt[tid];
            int a = (tid >= off) ? sm.u.a.cnt[tid - off] : 0;
            __syncthreads();
            sm.u.a.cnt[tid] = v + a;
            __syncthreads();
        }
        int total = sm.u.a.cnt[255];
        int base = sm.u.a.cnt[tid] - c;
#pragma unroll
        for (int j = 0; j < 4; ++j)
            if (st[j]) sm.u.a.runpos[base++] = p0 + j;
        if (tid == 0) sm.u.a.runpos[total] = LL;
        __syncthreads();

        int em = total - 1;               // trailing open run dropped
        ushort_t* arow = attn + ((size_t)b * EMAX + r) * HH;
        if (r >= em) {
            arow[tid] = 0; arow[tid + 256] = 0; arow[tid + 512] = 0;
        } else {
            int s = sm.u.a.runpos[r], e = sm.u.a.runpos[r + 1];
            float inv = 1.0f / (float)(e - s);
            const float* hb = h1 + (size_t)b * LL * HH;
            float a0 = 0.f, a1 = 0.f, a2 = 0.f;
            for (int p = s; p < e; ++p) {
                const float* row = hb + (size_t)p * HH;
                a0 += row[tid]; a1 += row[tid + 256]; a2 += row[tid + 512];
            }
            arow[tid]       = f2bf(a0 * inv);
            arow[tid + 256] = f2bf(a1 * inv);
            arow[tid + 512] = f2bf(a2 * inv);
        }
        __syncthreads();                   // all row stores issued & drained
        if (tid == 0)
            __hip_atomic_fetch_add(&done[b], 1, __ATOMIC_RELEASE,
                                   __HIP_MEMORY_SCOPE_AGENT);
        return;
    }

    if (bid >= NATTN + NGEMMB) {
        // ================= copy + fill =================
        int cid = bid - (NATTN + NGEMMB);  // 0..2047
        const float4v* in4 = (const float4v*)lm;
        float4v* out4 = (float4v*)out;
        int c = cid * 256 + tid;           // 0..524287
#pragma unroll
        for (int g = 0; g < 4; ++g) {
            size_t i0 = (size_t)(g * 4 + 0) * 524288 + c;
            size_t i1 = (size_t)(g * 4 + 1) * 524288 + c;
            size_t i2 = (size_t)(g * 4 + 2) * 524288 + c;
            size_t i3 = (size_t)(g * 4 + 3) * 524288 + c;
            float4v v0 = in4[i0];
            float4v v1 = in4[i1];
            float4v v2 = in4[i2];
            float4v v3 = in4[i3];
            out4[i0 + ((i0 >> 10) << 8)] = v0;   // out idx = i + row*256
            out4[i1 + ((i1 >> 10) << 8)] = v1;
            out4[i2 + ((i2 >> 10) << 8)] = v2;
            out4[i3 + ((i3 >> 10) << 8)] = v3;
        }
        float4v fv = {-100.f, -100.f, -100.f, -100.f};
        if (tid < 192) {
#pragma unroll
            for (int j = 0; j < 4; ++j) {
                size_t row = (size_t)cid * 4 + j;       // 0..8191
                out4[row * (OUTW / 4) + (VV + 256) / 4 + tid] = fv;
            }
        }
        return;
    }

    // ================= GEMM (spin-gated) =================
    int g    = bid - NATTN;
    int b    = g >> 4;
    int t2   = g & 15;
    int brow = (t2 >> 1) << 7;
    int bcol = (t2 & 1) << 7;

    // wait for this batch's 256 attn rows (acquire, agent scope)
    while (__hip_atomic_load(&done[b], __ATOMIC_ACQUIRE,
                             __HIP_MEMORY_SCOPE_AGENT) < 256)
        __builtin_amdgcn_s_sleep(8);
    __syncthreads();

    const int lane = tid & 63;
    const int wid  = tid >> 6;
    const int wr   = (wid >> 1) & 1;
    const int wc   = wid & 1;

    const float*    Ab = h2   + (size_t)b * LOO * HH;
    const ushort_t* Bb = attn + (size_t)b * EMAX * HH;

    f32x4 zero = {0.f, 0.f, 0.f, 0.f};
    f32x4 acc[4][4];
#pragma unroll
    for (int i = 0; i < 4; ++i)
#pragma unroll
        for (int j = 0; j < 4; ++j) acc[i][j] = zero;

    for (int k0 = 0; k0 < HH; k0 += 64) {
        __syncthreads();
        // A tile: 128x64 f32 = 32KB, 256B rows, 32B-granule XOR source swizzle
#pragma unroll
        for (int i = 0; i < 8; ++i) {
            int off = i * 4096 + tid * 16;
            int row = off >> 8;
            int cb  = off & 255;
            int scb = cb ^ ((row & 7) << 5);
            const float* ga = Ab + (size_t)(brow + row) * HH + k0 + (scb >> 2);
            __builtin_amdgcn_global_load_lds(
                (const __attribute__((address_space(1))) void*)ga,
                (__attribute__((address_space(3))) void*)(sm.u.g + off), 16, 0, 0);
        }
        // B tile: 128x64 bf16 = 16KB, 128B rows, 16B-granule XOR source swizzle
#pragma unroll
        for (int i = 0; i < 4; ++i) {
            int off = i * 4096 + tid * 16;
            int row = off >> 7;
            int cb  = off & 127;
            int scb = cb ^ ((row & 7) << 4);
            const ushort_t* gb = Bb + (size_t)(bcol + row) * HH + k0 + (scb >> 1);
            __builtin_amdgcn_global_load_lds(
                (const __attribute__((address_space(1))) void*)gb,
                (__attribute__((address_space(3))) void*)(sm.u.g + 32768 + off), 16, 0, 0);
        }
        asm volatile("s_waitcnt vmcnt(0)" ::: "memory");
        __syncthreads();

#pragma unroll
        for (int ks = 0; ks < 2; ++ks) {
            bf16x8 af[4], bfr[4];
#pragma unroll
            for (int mi = 0; mi < 4; ++mi) {
                int row  = (wr << 6) + (mi << 4) + (lane & 15);
                int colb = (ks << 7) + ((lane >> 4) << 5);        // f32 bytes
                int addr = (row << 8) + (colb ^ ((row & 7) << 5));
                f32x4 a0 = *(const f32x4*)(sm.u.g + addr);
                f32x4 a1 = *(const f32x4*)(sm.u.g + addr + 16);
                bf16x8 t;
                t[0] = (__bf16)a0[0]; t[1] = (__bf16)a0[1];
                t[2] = (__bf16)a0[2]; t[3] = (__bf16)a0[3];
                t[4] = (__bf16)a1[0]; t[5] = (__bf16)a1[1];
                t[6] = (__bf16)a1[2]; t[7] = (__bf16)a1[3];
                af[mi] = t;
            }
#pragma unroll
            for (int ni = 0; ni < 4; ++ni) {
                int row  = (wc << 6) + (ni << 4) + (lane & 15);
                int colb = (ks << 6) + ((lane >> 4) << 4);        // bf16 bytes
                int addr = (row << 7) + (colb ^ ((row & 7) << 4));
                bfr[ni] = *(const bf16x8*)(sm.u.g + 32768 + addr);
            }
#pragma unroll
            for (int mi = 0; mi < 4; ++mi)
#pragma unroll
                for (int ni = 0; ni < 4; ++ni)
                    acc[mi][ni] = __builtin_amdgcn_mfma_f32_16x16x32_bf16(
                        af[mi], bfr[ni], acc[mi][ni], 0, 0, 0);
        }
    }

    // epilogue: C/D layout col=lane&15, row=(lane>>4)*4+reg (m89-verified)
    // em = runs-1 is recoverable only from done path; recompute via tags? No:
    // bias column threshold em varies per batch; read from attn producer's
    // count: col >= em rows of attn are zero, so acc is zero there; bias -100
    // must still be selected. Store em per batch in done[b+8]... simpler:
    // producers wrote zeros for rows >= em, and we need em here: recompute
    // cheaply from tags row (uniform scalar loop over 1024 ints in L2).
    int em;
    {
        const int* tg = tags + b * LL;
        int cnt_runs = 0;
        int prev = -2;
        for (int p = tid; p < LL; p += 256) { }   // (placeholder, see below)
        // wave-cooperative run count: each thread counts starts in its stride
        int myc = 0;
        for (int p = tid; p < LL; p += 256) {
            int t  = tg[p];
            int pr = (p == 0) ? -2 : tg[p - 1];
            myc += (t != pr);
        }
        // block-reduce via LDS (reuse A region, pre-staging so safe? NO —
        // GEMM already used LDS; do wave reduce + readfirstlane per wave,
        // then cross-wave via ds after __syncthreads)
        __syncthreads();
        int* red = (int*)sm.u.g;
        red[tid] = myc;
        __syncthreads();
        if (tid < 128) red[tid] += red[tid + 128];
        __syncthreads();
        if (tid < 64) red[tid] += red[tid + 64];
        __syncthreads();
        if (tid < 32) { red[tid] += red[tid + 32]; }
        __syncthreads();
        if (tid < 16) { red[tid] += red[tid + 16]; }
        __syncthreads();
        if (tid < 8) { red[tid] += red[tid + 8]; }
        __syncthreads();
        if (tid < 4) { red[tid] += red[tid + 4]; }
        __syncthreads();
        if (tid < 2) { red[tid] += red[tid + 2]; }
        __syncthreads();
        cnt_runs = red[0] + red[1];
        em = cnt_runs - 1;
    }

    float* outb = out + (size_t)b * LOO * OUTW + VV;
#pragma unroll
    for (int mi = 0; mi < 4; ++mi) {
        int rbase = brow + (wr << 6) + (mi << 4) + ((lane >> 4) << 2);
#pragma unroll
        for (int ni = 0; ni < 4; ++ni) {
            int col = bcol + (wc << 6) + (ni << 4) + (lane & 15);
            float badd = (col < em) ? 0.0f : -100.0f;
#pragma unroll
            for (int rr = 0; rr < 4; ++rr)
                outb[(size_t)(rbase + rr) * OUTW + col] = acc[mi][ni][rr] + badd;
        }
    }
}

extern "C" void kernel_launch(void* const* d_in, const int* in_sizes, int n_in,
                              void* d_out, int out_size, void* d_ws, size_t ws_size,
                              hipStream_t stream) {
    const float* h1   = (const float*)d_in[0];   // [8,1024,768]
    const float* h2   = (const float*)d_in[1];   // [8,1024,768]
    const float* lm   = (const float*)d_in[2];   // [8,1024,4096]
    const int*   tags = (const int*)d_in[3];     // [8,1024]
    float* out = (float*)d_out;                  // [8,1024,5120]

    char* ws = (char*)d_ws;
    ushort_t* attn = (ushort_t*)ws;              // 3,145,728 B
    int*      done = (int*)(ws + 3145728);       // 32 B, zeroed each call

    hipMemsetAsync(done, 0, BB * sizeof(int), stream);
    mega_kernel<<<NATTN + NGEMMB + NCOPY, 256, 0, stream>>>(
        h1, h2, lm, tags, attn, done, out);
}